// Round 9
// baseline (5967.863 us; speedup 1.0000x reference)
//
#include <hip/hip_runtime.h>
#include <hip/hip_bf16.h>
#include <hip/hip_fp16.h>

// Problem constants
#define B_ 64
#define T_ 512
#define D_ 256
#define H_ 512
#define M_ (B_*T_)          // 32768

#define NBLK 64             // scan blocks
#define JO 8                // hidden columns owned per scan block

typedef unsigned int uint;
typedef __attribute__((ext_vector_type(8))) short bf16x8;
typedef __attribute__((ext_vector_type(4))) float f32x4;
typedef _Float16 half_t;
typedef __attribute__((ext_vector_type(2))) _Float16 half2_t;

__device__ __forceinline__ unsigned short f32_to_bf16(float f) {
    unsigned u = __builtin_bit_cast(unsigned, f);
    unsigned r = (u + 0x7fffu + ((u >> 16) & 1u)) >> 16;
    return (unsigned short)r;
}
__device__ __forceinline__ float bf16_to_f32(unsigned short h) {
    unsigned u = ((unsigned)h) << 16;
    return __builtin_bit_cast(float, u);
}
__device__ __forceinline__ unsigned pkh2(float a, float b) {
    half2_t h; h.x = (half_t)a; h.y = (half_t)b;
    return __builtin_bit_cast(unsigned, h);
}
__device__ __forceinline__ half2_t uph2(unsigned u) {
    return __builtin_bit_cast(half2_t, u);
}

#if __has_builtin(__builtin_amdgcn_fdot2)
__device__ __forceinline__ float fdot2(half2_t a, half2_t b, float c) {
    return __builtin_amdgcn_fdot2(a, b, c, false);
}
#else
__device__ __forceinline__ float fdot2(half2_t a, half2_t b, float c) {
    return c + (float)a.x * (float)b.x + (float)a.y * (float)b.y;
}
#endif

// agent-scope (cross-XCD coherent, L2-bypassing) relaxed atomics
__device__ __forceinline__ uint ald(const uint* p) {
    return __hip_atomic_load(p, __ATOMIC_RELAXED, __HIP_MEMORY_SCOPE_AGENT);
}
__device__ __forceinline__ void ast(uint* p, uint v) {
    __hip_atomic_store(p, v, __ATOMIC_RELAXED, __HIP_MEMORY_SCOPE_AGENT);
}

__device__ __forceinline__ float sigmoidf_(float x) {
    return 1.f / (1.f + __expf(-x));
}

// ---------------------------------------------------------------------------
// P = We2h @ W  for r and z gates
// ---------------------------------------------------------------------------
__global__ void comp_p(const float* __restrict__ We2h, const float* __restrict__ Wre,
                       const float* __restrict__ Wze,
                       float* __restrict__ Pr, float* __restrict__ Pz) {
    int tid = blockIdx.x * blockDim.x + threadIdx.x;   // 256*512
    if (tid >= 256 * 512) return;
    int k = tid >> 9, j = tid & 511;
    float ar = 0.f, az = 0.f;
    for (int kk = 0; kk < 512; kk++) {
        float e = We2h[k * 512 + kk];
        ar += e * Wre[kk * 512 + j];
        az += e * Wze[kk * 512 + j];
    }
    Pr[tid] = ar;
    Pz[tid] = az;
}

// ---------------------------------------------------------------------------
// Build bf16 weights for the big GEMMs.
// ---------------------------------------------------------------------------
__global__ void build_wt(const float* __restrict__ We2h, const float* __restrict__ Wrx,
                         const float* __restrict__ Wzx, const float* __restrict__ Wnx,
                         const float* __restrict__ Pr, const float* __restrict__ Pz,
                         const float* __restrict__ br, const float* __restrict__ bz,
                         const float* __restrict__ bn, const float* __restrict__ Wo,
                         unsigned short* __restrict__ WcatT, float* __restrict__ biascat,
                         unsigned short* __restrict__ WoT) {
    int tid = blockIdx.x * blockDim.x + threadIdx.x;
    const int total1 = 2048 * 256;
    if (tid < total1) {
        int n = tid >> 8, k = tid & 255;
        int sel = n >> 9, nl = n & 511;
        float v;
        if (sel == 0)      v = We2h[k * 512 + nl];
        else if (sel == 1) v = Wrx[k * 512 + nl] + Pr[k * 512 + nl];
        else if (sel == 2) v = Wzx[k * 512 + nl] + Pz[k * 512 + nl];
        else               v = Wnx[k * 512 + nl];
        WcatT[tid] = f32_to_bf16(v);
        if (k == 0) {
            float bv = sel == 0 ? 0.f : sel == 1 ? br[nl] : sel == 2 ? bz[nl] : bn[nl];
            biascat[n] = bv;
        }
    } else {
        int t2 = tid - total1;
        if (t2 < 256 * 512) {
            int n = t2 >> 9, k = t2 & 511;
            WoT[t2] = f32_to_bf16(Wo[k * 256 + n]);
        }
    }
}

// ---------------------------------------------------------------------------
// Packed f16 recurrent weights (transformed):
//  warz uint2 [256 kp][512 j]: {pkh2(Ar[2kp],Ar[2kp+1]), pkh2(Az...)}, A=Wh-We
//  wan  uint  [512 k][512 j]:  pkh2(An[k][j], Wne[k][j]),  An = Wnh - Wne
// ---------------------------------------------------------------------------
__global__ void build_wscan(const float* __restrict__ Wrh, const float* __restrict__ Wre,
                            const float* __restrict__ Wzh, const float* __restrict__ Wze,
                            const float* __restrict__ Wnh, const float* __restrict__ Wne,
                            uint2* __restrict__ warz, uint* __restrict__ wan) {
    int tid = blockIdx.x * blockDim.x + threadIdx.x;
    if (tid < 256 * 512) {
        int kp = tid >> 9, j = tid & 511;
        int k0 = 2 * kp;
        float ar0 = Wrh[k0 * 512 + j] - Wre[k0 * 512 + j];
        float ar1 = Wrh[(k0 + 1) * 512 + j] - Wre[(k0 + 1) * 512 + j];
        float az0 = Wzh[k0 * 512 + j] - Wze[k0 * 512 + j];
        float az1 = Wzh[(k0 + 1) * 512 + j] - Wze[(k0 + 1) * 512 + j];
        warz[tid] = make_uint2(pkh2(ar0, ar1), pkh2(az0, az1));
    }
    int t2 = tid - 256 * 512;
    if (t2 >= 0 && t2 < 512 * 512) {
        int k = t2 >> 9, j = t2 & 511;
        float an = Wnh[k * 512 + j] - Wne[k * 512 + j];
        wan[t2] = pkh2(an, Wne[k * 512 + j]);
    }
}

// ---------------------------------------------------------------------------
// init hbuf: [256 kp][64 m] uint = (f16 h[m][2kp], f16 h[m][2kp+1])
// ---------------------------------------------------------------------------
__global__ void init_hbuf(const float* __restrict__ h0, uint* __restrict__ hbuf) {
    int tid = blockIdx.x * blockDim.x + threadIdx.x;   // 256*64
    if (tid >= 256 * 64) return;
    int kp = tid >> 6, m = tid & 63;
    hbuf[tid] = pkh2(h0[m * 512 + 2 * kp], h0[m * 512 + 2 * kp + 1]);
}

// ---------------------------------------------------------------------------
// GEMM-X: writes xproj directly in scan layout xT[t][col][m] bf16.
// ---------------------------------------------------------------------------
__global__ __launch_bounds__(256)
void gemmx_kernel(const float* __restrict__ A, const unsigned short* __restrict__ BT,
                  const float* __restrict__ bias, unsigned short* __restrict__ xT) {
    __shared__ unsigned short Asm[128 * 64];
    __shared__ unsigned short Bsm[128 * 64];
    __shared__ unsigned short Csm[128][128];   // [col][row]
    const int tid = threadIdx.x;
    const int t0 = blockIdx.x * 2;        // time-pair
    const int c0 = blockIdx.y * 128;      // col tile
    const int lane = tid & 63, wid = tid >> 6;
    const int wm = wid >> 1, wn = wid & 1;
    const int lr = lane & 15, lg = lane >> 4;

    f32x4 acc[4][4] = {};

    const int srow = tid >> 1, shalf = tid & 1;
    const int rowA = (srow & 63) * 512 + t0 + (srow >> 6);     // (b,t) -> A row
    const float* Arow = A + (size_t)rowA * 256 + shalf * 32;
    const unsigned short* Brow = BT + (size_t)(c0 + srow) * 256 + shalf * 32;
    unsigned short* As = &Asm[srow * 64 + shalf * 32];
    unsigned short* Bs = &Bsm[srow * 64 + shalf * 32];

    for (int kt = 0; kt < 256; kt += 64) {
#pragma unroll
        for (int q = 0; q < 8; q++) {
            float4 v = *(const float4*)(Arow + kt + q * 4);
            unsigned p0 = ((unsigned)f32_to_bf16(v.y) << 16) | f32_to_bf16(v.x);
            unsigned p1 = ((unsigned)f32_to_bf16(v.w) << 16) | f32_to_bf16(v.z);
            *(uint2*)(As + q * 4) = make_uint2(p0, p1);
        }
#pragma unroll
        for (int q = 0; q < 4; q++) {
            uint4 v = *(const uint4*)(Brow + kt + q * 8);
            *(uint4*)(Bs + q * 8) = v;
        }
        __syncthreads();
#pragma unroll
        for (int ks = 0; ks < 2; ks++) {
            bf16x8 af[4], bfr[4];
#pragma unroll
            for (int m = 0; m < 4; m++)
                af[m] = *(const bf16x8*)&Asm[(wm * 64 + m * 16 + lr) * 64 + ks * 32 + lg * 8];
#pragma unroll
            for (int n2 = 0; n2 < 4; n2++)
                bfr[n2] = *(const bf16x8*)&Bsm[(wn * 64 + n2 * 16 + lr) * 64 + ks * 32 + lg * 8];
#pragma unroll
            for (int m = 0; m < 4; m++)
#pragma unroll
                for (int n2 = 0; n2 < 4; n2++)
                    acc[m][n2] = __builtin_amdgcn_mfma_f32_16x16x32_bf16(
                        af[m], bfr[n2], acc[m][n2], 0, 0, 0);
        }
        __syncthreads();
    }
#pragma unroll
    for (int m = 0; m < 4; m++) {
        int r0 = wm * 64 + m * 16 + lg * 4;
#pragma unroll
        for (int n2 = 0; n2 < 4; n2++) {
            int c = wn * 64 + n2 * 16 + lr;
            float bv = bias[c0 + c];
#pragma unroll
            for (int i = 0; i < 4; i++)
                Csm[c][r0 + i] = f32_to_bf16(acc[m][n2][i] + bv);
        }
    }
    __syncthreads();
#pragma unroll
    for (int th = 0; th < 2; th++) {
        uint4* dst = (uint4*)(xT + ((size_t)(t0 + th) * 2048 + c0) * 64);
        for (int q = tid; q < 1024; q += 256) {
            int c = q >> 3, b0 = (q & 7) * 8;
            dst[q] = *(const uint4*)&Csm[c][th * 64 + b0];
        }
        __syncthreads();
    }
}

// ---------------------------------------------------------------------------
// Readout GEMM: A fp32 [M][K], BT bf16 [N][K], C fp32 + bias.
// ---------------------------------------------------------------------------
__global__ __launch_bounds__(256)
void gemm_out_kernel(const float* __restrict__ A, const unsigned short* __restrict__ BT,
                     const float* __restrict__ bias, float* __restrict__ C,
                     int M, int N, int K) {
    __shared__ unsigned short Asm[128 * 64];
    __shared__ unsigned short Bsm[128 * 64];
    const int tid = threadIdx.x;
    const int bm = blockIdx.x, bn = blockIdx.y;
    const int lane = tid & 63, wid = tid >> 6;
    const int wm = wid >> 1, wn = wid & 1;
    const int lr = lane & 15, lg = lane >> 4;

    f32x4 acc[4][4] = {};

    const int srow = tid >> 1, shalf = tid & 1;
    const float* Arow = A + (size_t)(bm * 128 + srow) * K + shalf * 32;
    const unsigned short* Brow = BT + (size_t)(bn * 128 + srow) * K + shalf * 32;
    unsigned short* As = &Asm[srow * 64 + shalf * 32];
    unsigned short* Bs = &Bsm[srow * 64 + shalf * 32];

    for (int kt = 0; kt < K; kt += 64) {
#pragma unroll
        for (int q = 0; q < 8; q++) {
            float4 v = *(const float4*)(Arow + kt + q * 4);
            unsigned p0 = ((unsigned)f32_to_bf16(v.y) << 16) | f32_to_bf16(v.x);
            unsigned p1 = ((unsigned)f32_to_bf16(v.w) << 16) | f32_to_bf16(v.z);
            *(uint2*)(As + q * 4) = make_uint2(p0, p1);
        }
#pragma unroll
        for (int q = 0; q < 4; q++) {
            uint4 v = *(const uint4*)(Brow + kt + q * 8);
            *(uint4*)(Bs + q * 8) = v;
        }
        __syncthreads();
#pragma unroll
        for (int ks = 0; ks < 2; ks++) {
            bf16x8 af[4], bfr[4];
#pragma unroll
            for (int m = 0; m < 4; m++)
                af[m] = *(const bf16x8*)&Asm[(wm * 64 + m * 16 + lr) * 64 + ks * 32 + lg * 8];
#pragma unroll
            for (int n2 = 0; n2 < 4; n2++)
                bfr[n2] = *(const bf16x8*)&Bsm[(wn * 64 + n2 * 16 + lr) * 64 + ks * 32 + lg * 8];
#pragma unroll
            for (int m = 0; m < 4; m++)
#pragma unroll
                for (int n2 = 0; n2 < 4; n2++)
                    acc[m][n2] = __builtin_amdgcn_mfma_f32_16x16x32_bf16(
                        af[m], bfr[n2], acc[m][n2], 0, 0, 0);
        }
        __syncthreads();
    }
#pragma unroll
    for (int m = 0; m < 4; m++) {
        int row0 = bm * 128 + wm * 64 + m * 16 + lg * 4;
#pragma unroll
        for (int n2 = 0; n2 < 4; n2++) {
            int col = bn * 128 + wn * 64 + n2 * 16 + lr;
            float bv = bias[col];
#pragma unroll
            for (int i = 0; i < 4; i++)
                C[(size_t)(row0 + i) * N + col] = acc[m][n2][i] + bv;
        }
    }
}

// ---------------------------------------------------------------------------
// Grid-synced weight-stationary scan, batch-half software pipelining.
// 64 blocks x 512 threads; block owns j = bid*8..+8 for ALL batches.
// B=64 split into halves (m 0-31 / 32-63) with disjoint exchange buffers and
// flag sets. Schedule per step: A(h0),flagA0; A(h1),flagA1; waitA0,B(h0),
// flagH0; waitA1,B(h1),flagH1 -- each flag's L3 RTT hides under the other
// half's compute. Flag sets (monotonic): 0=A-h0, 1=A-h1, 2=H-h0, 3=H-h1,
// each at flags[set*256 + bid*4].
// Half-phase lane map: ml = lane&31 (batch within half), kq = lane>>5
// (k-row parity) -> full 64-lane utilization; 2-addr LDS broadcast is free;
// __shfl_xor(32) combines the kq-partials.
// ---------------------------------------------------------------------------
__global__ __launch_bounds__(512)
void scan_sync(const unsigned short* __restrict__ xT,   // [512 t][2048 col][64 m] bf16
               const float* __restrict__ h0,            // [64 m][512 j]
               const uint2* __restrict__ warz,          // [256 kp][512 j]
               const uint* __restrict__ wan,            // [512 k][512 j]
               uint* __restrict__ hbuf,                 // [256 kp][64 m]
               uint* __restrict__ rhrxe,                // [512 k][64 m]
               uint* __restrict__ flags,                // [4*256]
               float* __restrict__ hseq)                // [64 m][512 t][512 j]
{
    __shared__ uint2 Wrz_l[256][JO];                    // 16 KB
    __shared__ uint  Wn_l[512][JO];                     // 16 KB
    __shared__ float part[3][8][JO][32];                // 24 KB
    __shared__ float h_loc[JO][64], z_loc[JO][64];      // 4 KB

    const int bid = blockIdx.x, tid = threadIdx.x;
    const int lane = tid & 63, wv = tid >> 6;           // 8 waves
    const int j0 = bid * JO;
    const int jF = tid >> 6, mF = tid & 63;             // per-thread gate/state map
    const int ml = lane & 31, kq = lane >> 5;           // half-phase lane map

    // one-time: weights -> LDS, local h slice
    for (int i = tid; i < 256 * JO; i += 512) {
        int kp = i >> 3, j = i & 7;
        Wrz_l[kp][j] = warz[kp * 512 + j0 + j];
    }
    for (int i = tid; i < 512 * JO; i += 512) {
        int k = i >> 3, j = i & 7;
        Wn_l[k][j] = wan[k * 512 + j0 + j];
    }
    h_loc[jF][mF] = h0[mF * 512 + j0 + jF];
    __syncthreads();

    const int jg = j0 + jF;
    const size_t xoff = (size_t)jg * 64 + mF;

    for (int t = 0; t < T_; t++) {
        // per-thread xT gate loads (hidden under waitH0 + phase A0)
        const size_t xb = (size_t)t * 2048 * 64 + xoff;
        unsigned short pxe = xT[xb];
        unsigned short pxr = xT[xb + (size_t)512 * 64];
        unsigned short pxz = xT[xb + (size_t)1024 * 64];
        unsigned short pxn = xT[xb + (size_t)1536 * 64];

#pragma unroll
        for (int mh = 0; mh < 2; mh++) {
            // ---- wait: hbuf(mh) of step t-1 published by all blocks ----
            if (tid < 64) {
                int it = 0; uint f;
                do {
                    f = ald(&flags[(2 + mh) * 256 + tid * 4]);
                    if (++it > (1 << 24)) break;       // fail loud, not hang
                } while (!__all(f >= (uint)t));
            }
            __builtin_amdgcn_s_barrier();

            // ---- phase A(mh): r,z partial dots; wave wv covers kp range 32
            uint hv[16];
#pragma unroll
            for (int q = 0; q < 16; q++)
                hv[q] = ald(&hbuf[(wv * 32 + 2 * q + kq) * 64 + mh * 32 + ml]);
            float ar[JO] = {}, az[JO] = {};
#pragma unroll
            for (int q = 0; q < 16; q++) {
                half2_t h2 = uph2(hv[q]);
                const int kp = wv * 32 + 2 * q + kq;
#pragma unroll
                for (int j = 0; j < JO; j++) {
                    uint2 w = *(const uint2*)&Wrz_l[kp][j];
                    ar[j] = fdot2(h2, uph2(w.x), ar[j]);
                    az[j] = fdot2(h2, uph2(w.y), az[j]);
                }
            }
#pragma unroll
            for (int j = 0; j < JO; j++) {
                ar[j] += __shfl_xor(ar[j], 32);
                az[j] += __shfl_xor(az[j], 32);
            }
            if (lane < 32) {
#pragma unroll
                for (int j = 0; j < JO; j++) {
                    part[0][wv][j][ml] = ar[j];
                    part[1][wv][j][ml] = az[j];
                }
            }
            __syncthreads();

            // ---- finalize A(mh): sigmoid, publish (r*h, r*xe) ----
            if ((mF >> 5) == mh) {
                float sr = 0.f, sz = 0.f;
#pragma unroll
                for (int w = 0; w < 8; w++) {
                    sr += part[0][w][jF][mF & 31];
                    sz += part[1][w][jF][mF & 31];
                }
                float r = sigmoidf_(bf16_to_f32(pxr) + sr);
                float z = sigmoidf_(bf16_to_f32(pxz) + sz);
                float h = h_loc[jF][mF];
                z_loc[jF][mF] = z;
                ast(&rhrxe[jg * 64 + mF], pkh2(r * h, r * bf16_to_f32(pxe)));
            }
            __syncthreads();                           // drain rhrxe stores
            if (tid == 0) ast(&flags[mh * 256 + bid * 4], (uint)t + 1u);
        }

#pragma unroll
        for (int mh = 0; mh < 2; mh++) {
            // ---- wait: rhrxe(mh) of step t published by all blocks ----
            if (tid < 64) {
                int it = 0; uint f;
                do {
                    f = ald(&flags[mh * 256 + tid * 4]);
                    if (++it > (1 << 24)) break;
                } while (!__all(f >= (uint)t + 1u));
            }
            __builtin_amdgcn_s_barrier();

            // ---- phase B(mh): n partial dots; wave wv covers k range 64 ----
            uint rv[32];
#pragma unroll
            for (int q = 0; q < 32; q++)
                rv[q] = ald(&rhrxe[(wv * 64 + 2 * q + kq) * 64 + mh * 32 + ml]);
            float an[JO] = {};
#pragma unroll
            for (int q = 0; q < 32; q++) {
                half2_t p2 = uph2(rv[q]);
                const int k = wv * 64 + 2 * q + kq;
#pragma unroll
                for (int j = 0; j < JO; j++)
                    an[j] = fdot2(p2, uph2(Wn_l[k][j]), an[j]);
            }
#pragma unroll
            for (int j = 0; j < JO; j++) an[j] += __shfl_xor(an[j], 32);
            if (lane < 32) {
#pragma unroll
                for (int j = 0; j < JO; j++) part[2][wv][j][ml] = an[j];
            }
            __syncthreads();

            // ---- finalize B(mh): tanh, h update ----
            if ((mF >> 5) == mh) {
                float sn = 0.f;
#pragma unroll
                for (int w = 0; w < 8; w++) sn += part[2][w][jF][mF & 31];
                float nn = tanhf(bf16_to_f32(pxn) + sn);
                float z = z_loc[jF][mF];
                float h = h_loc[jF][mF];
                h_loc[jF][mF] = (1.f - z) * h + z * nn;
            }
            __syncthreads();

            // ---- publish new h (f16 pairs) + hseq (32B bursts) ----
            if (((mF >> 5) == mh) && ((jF & 1) == 0))
                ast(&hbuf[(bid * 4 + (jF >> 1)) * 64 + mF],
                    pkh2(h_loc[jF][mF], h_loc[jF + 1][mF]));
            {
                int js = tid & 7, ms = tid >> 3;
                if ((ms >> 5) == mh)
                    hseq[((size_t)ms * 512 + t) * 512 + j0 + js] = h_loc[js][ms];
            }
            __syncthreads();                           // drain publishes
            if (tid == 0) ast(&flags[(2 + mh) * 256 + bid * 4], (uint)t + 1u);
        }
    }
}

// ---------------------------------------------------------------------------
extern "C" void kernel_launch(void* const* d_in, const int* in_sizes, int n_in,
                              void* d_out, int out_size, void* d_ws, size_t ws_size,
                              hipStream_t stream) {
    const float* x    = (const float*)d_in[0];
    const float* h0   = (const float*)d_in[1];
    const float* We2h = (const float*)d_in[2];
    const float* Wrx  = (const float*)d_in[3];
    const float* Wrh  = (const float*)d_in[4];
    const float* Wre  = (const float*)d_in[5];
    const float* br   = (const float*)d_in[6];
    const float* Wzx  = (const float*)d_in[7];
    const float* Wzh  = (const float*)d_in[8];
    const float* Wze  = (const float*)d_in[9];
    const float* bz   = (const float*)d_in[10];
    const float* Wnx  = (const float*)d_in[11];
    const float* Wnh  = (const float*)d_in[12];
    const float* Wne  = (const float*)d_in[13];
    const float* bn   = (const float*)d_in[14];
    const float* Wo   = (const float*)d_in[15];
    const float* bo   = (const float*)d_in[16];

    // workspace layout (bytes)
    char* w = (char*)d_ws;
    unsigned short* xT    = (unsigned short*)(w);                  // 134217728
    uint2*          warz  = (uint2*)(w + 134217728);               // 1048576
    uint*           wan   = (uint*)(w + 135266304);                // 1048576
    unsigned short* WcatT = (unsigned short*)(w + 136314880);      // 1048576
    unsigned short* WoT   = (unsigned short*)(w + 137363456);      // 262144
    float*          biascat = (float*)(w + 137625600);             // 8192
    float*          Pr    = (float*)(w + 137633792);               // 524288
    float*          Pz    = (float*)(w + 138158080);               // 524288
    uint*           hbuf  = (uint*)(w + 138682368);                // 65536
    uint*           rhrxe = (uint*)(w + 138747904);                // 131072
    uint*           flags = (uint*)(w + 138878976);                // 4096 (4 sets)

    float* out  = (float*)d_out;                    // [B,T,D]
    float* hseq = (float*)d_out + (size_t)M_ * D_;  // [B,T,H]

    hipMemsetAsync(flags, 0, 4 * 256 * sizeof(uint), stream);

    // 1. composite input weights + packed scan weights
    comp_p<<<(256 * 512 + 255) / 256, 256, 0, stream>>>(We2h, Wre, Wze, Pr, Pz);
    build_wt<<<(2048 * 256 + 256 * 512 + 255) / 256, 256, 0, stream>>>(
        We2h, Wrx, Wzx, Wnx, Pr, Pz, br, bz, bn, Wo, WcatT, biascat, WoT);
    build_wscan<<<(256 * 512 + 512 * 512 + 255) / 256, 256, 0, stream>>>(
        Wrh, Wre, Wzh, Wze, Wnh, Wne, warz, wan);
    init_hbuf<<<(256 * 64 + 255) / 256, 256, 0, stream>>>(h0, hbuf);

    // 2. pre-projections directly into xT[t][col][m]
    {
        dim3 grid(T_ / 2, 2048 / 128);
        gemmx_kernel<<<grid, 256, 0, stream>>>(x, WcatT, biascat, xT);
    }
    // 3. grid-synced scan -> hseq
    scan_sync<<<NBLK, 512, 0, stream>>>(xT, h0, warz, wan, hbuf, rhrxe, flags, hseq);
    // 4. readout: [32768,512] @ [512,256] + bo -> out
    {
        dim3 grid(M_ / 128, D_ / 128);
        gemm_out_kernel<<<grid, 256, 0, stream>>>(hseq, WoT, bo, out, M_, D_, H_);
    }
}

// Round 11
// 4997.332 us; speedup vs baseline: 1.1942x; 1.1942x over previous
//
#include <hip/hip_runtime.h>
#include <hip/hip_bf16.h>
#include <hip/hip_fp16.h>

// Problem constants
#define B_ 64
#define T_ 512
#define D_ 256
#define H_ 512
#define M_ (B_*T_)          // 32768

#define NBLK 64             // scan blocks
#define JO 8                // hidden columns owned per scan block

typedef unsigned int uint;
typedef __attribute__((ext_vector_type(8))) short bf16x8;
typedef __attribute__((ext_vector_type(4))) float f32x4;
typedef _Float16 half_t;
typedef __attribute__((ext_vector_type(2))) _Float16 half2_t;

__device__ __forceinline__ unsigned short f32_to_bf16(float f) {
    unsigned u = __builtin_bit_cast(unsigned, f);
    unsigned r = (u + 0x7fffu + ((u >> 16) & 1u)) >> 16;
    return (unsigned short)r;
}
__device__ __forceinline__ float bf16_to_f32(unsigned short h) {
    unsigned u = ((unsigned)h) << 16;
    return __builtin_bit_cast(float, u);
}
__device__ __forceinline__ unsigned pkh2(float a, float b) {
    half2_t h; h.x = (half_t)a; h.y = (half_t)b;
    return __builtin_bit_cast(unsigned, h);
}
__device__ __forceinline__ half2_t uph2(unsigned u) {
    return __builtin_bit_cast(half2_t, u);
}

#if __has_builtin(__builtin_amdgcn_fdot2)
__device__ __forceinline__ float fdot2(half2_t a, half2_t b, float c) {
    return __builtin_amdgcn_fdot2(a, b, c, false);
}
#else
__device__ __forceinline__ float fdot2(half2_t a, half2_t b, float c) {
    return c + (float)a.x * (float)b.x + (float)a.y * (float)b.y;
}
#endif

// agent-scope (cross-XCD coherent, L2-bypassing) relaxed atomics
__device__ __forceinline__ uint ald(const uint* p) {
    return __hip_atomic_load(p, __ATOMIC_RELAXED, __HIP_MEMORY_SCOPE_AGENT);
}
__device__ __forceinline__ void ast(uint* p, uint v) {
    __hip_atomic_store(p, v, __ATOMIC_RELAXED, __HIP_MEMORY_SCOPE_AGENT);
}

__device__ __forceinline__ float sigmoidf_(float x) {
    return 1.f / (1.f + __expf(-x));
}

// Compile-time ordering edge after a relaxed spin (guide rule #18): prevents
// LLVM from hoisting the subsequent relaxed data loads above the spin loop.
// Zero runtime cost. (Rounds 7/8 got this implicitly from s_barrier; round 10
// removed it and raced.)
__device__ __forceinline__ void spin_fence() {
    asm volatile("" ::: "memory");
    __builtin_amdgcn_sched_barrier(0);
}

// ---------------------------------------------------------------------------
// P = We2h @ W  for r and z gates
// ---------------------------------------------------------------------------
__global__ void comp_p(const float* __restrict__ We2h, const float* __restrict__ Wre,
                       const float* __restrict__ Wze,
                       float* __restrict__ Pr, float* __restrict__ Pz) {
    int tid = blockIdx.x * blockDim.x + threadIdx.x;   // 256*512
    if (tid >= 256 * 512) return;
    int k = tid >> 9, j = tid & 511;
    float ar = 0.f, az = 0.f;
    for (int kk = 0; kk < 512; kk++) {
        float e = We2h[k * 512 + kk];
        ar += e * Wre[kk * 512 + j];
        az += e * Wze[kk * 512 + j];
    }
    Pr[tid] = ar;
    Pz[tid] = az;
}

// ---------------------------------------------------------------------------
// Build bf16 weights for the big GEMMs.
// ---------------------------------------------------------------------------
__global__ void build_wt(const float* __restrict__ We2h, const float* __restrict__ Wrx,
                         const float* __restrict__ Wzx, const float* __restrict__ Wnx,
                         const float* __restrict__ Pr, const float* __restrict__ Pz,
                         const float* __restrict__ br, const float* __restrict__ bz,
                         const float* __restrict__ bn, const float* __restrict__ Wo,
                         unsigned short* __restrict__ WcatT, float* __restrict__ biascat,
                         unsigned short* __restrict__ WoT) {
    int tid = blockIdx.x * blockDim.x + threadIdx.x;
    const int total1 = 2048 * 256;
    if (tid < total1) {
        int n = tid >> 8, k = tid & 255;
        int sel = n >> 9, nl = n & 511;
        float v;
        if (sel == 0)      v = We2h[k * 512 + nl];
        else if (sel == 1) v = Wrx[k * 512 + nl] + Pr[k * 512 + nl];
        else if (sel == 2) v = Wzx[k * 512 + nl] + Pz[k * 512 + nl];
        else               v = Wnx[k * 512 + nl];
        WcatT[tid] = f32_to_bf16(v);
        if (k == 0) {
            float bv = sel == 0 ? 0.f : sel == 1 ? br[nl] : sel == 2 ? bz[nl] : bn[nl];
            biascat[n] = bv;
        }
    } else {
        int t2 = tid - total1;
        if (t2 < 256 * 512) {
            int n = t2 >> 9, k = t2 & 511;
            WoT[t2] = f32_to_bf16(Wo[k * 256 + n]);
        }
    }
}

// ---------------------------------------------------------------------------
// Packed f16 recurrent weights (transformed):
//  warz uint2 [256 kp][512 j]: {pkh2(Ar[2kp],Ar[2kp+1]), pkh2(Az...)}, A=Wh-We
//  wan  uint  [512 k][512 j]:  pkh2(An[k][j], Wne[k][j]),  An = Wnh - Wne
// ---------------------------------------------------------------------------
__global__ void build_wscan(const float* __restrict__ Wrh, const float* __restrict__ Wre,
                            const float* __restrict__ Wzh, const float* __restrict__ Wze,
                            const float* __restrict__ Wnh, const float* __restrict__ Wne,
                            uint2* __restrict__ warz, uint* __restrict__ wan) {
    int tid = blockIdx.x * blockDim.x + threadIdx.x;
    if (tid < 256 * 512) {
        int kp = tid >> 9, j = tid & 511;
        int k0 = 2 * kp;
        float ar0 = Wrh[k0 * 512 + j] - Wre[k0 * 512 + j];
        float ar1 = Wrh[(k0 + 1) * 512 + j] - Wre[(k0 + 1) * 512 + j];
        float az0 = Wzh[k0 * 512 + j] - Wze[k0 * 512 + j];
        float az1 = Wzh[(k0 + 1) * 512 + j] - Wze[(k0 + 1) * 512 + j];
        warz[tid] = make_uint2(pkh2(ar0, ar1), pkh2(az0, az1));
    }
    int t2 = tid - 256 * 512;
    if (t2 >= 0 && t2 < 512 * 512) {
        int k = t2 >> 9, j = t2 & 511;
        float an = Wnh[k * 512 + j] - Wne[k * 512 + j];
        wan[t2] = pkh2(an, Wne[k * 512 + j]);
    }
}

// ---------------------------------------------------------------------------
// init hbuf: [256 kp][64 m] uint = (f16 h[m][2kp], f16 h[m][2kp+1])
// ---------------------------------------------------------------------------
__global__ void init_hbuf(const float* __restrict__ h0, uint* __restrict__ hbuf) {
    int tid = blockIdx.x * blockDim.x + threadIdx.x;   // 256*64
    if (tid >= 256 * 64) return;
    int kp = tid >> 6, m = tid & 63;
    hbuf[tid] = pkh2(h0[m * 512 + 2 * kp], h0[m * 512 + 2 * kp + 1]);
}

// ---------------------------------------------------------------------------
// GEMM-X: writes xproj directly in scan layout xT[t][col][m] bf16.
// ---------------------------------------------------------------------------
__global__ __launch_bounds__(256)
void gemmx_kernel(const float* __restrict__ A, const unsigned short* __restrict__ BT,
                  const float* __restrict__ bias, unsigned short* __restrict__ xT) {
    __shared__ unsigned short Asm[128 * 64];
    __shared__ unsigned short Bsm[128 * 64];
    __shared__ unsigned short Csm[128][128];   // [col][row]
    const int tid = threadIdx.x;
    const int t0 = blockIdx.x * 2;        // time-pair
    const int c0 = blockIdx.y * 128;      // col tile
    const int lane = tid & 63, wid = tid >> 6;
    const int wm = wid >> 1, wn = wid & 1;
    const int lr = lane & 15, lg = lane >> 4;

    f32x4 acc[4][4] = {};

    const int srow = tid >> 1, shalf = tid & 1;
    const int rowA = (srow & 63) * 512 + t0 + (srow >> 6);     // (b,t) -> A row
    const float* Arow = A + (size_t)rowA * 256 + shalf * 32;
    const unsigned short* Brow = BT + (size_t)(c0 + srow) * 256 + shalf * 32;
    unsigned short* As = &Asm[srow * 64 + shalf * 32];
    unsigned short* Bs = &Bsm[srow * 64 + shalf * 32];

    for (int kt = 0; kt < 256; kt += 64) {
#pragma unroll
        for (int q = 0; q < 8; q++) {
            float4 v = *(const float4*)(Arow + kt + q * 4);
            unsigned p0 = ((unsigned)f32_to_bf16(v.y) << 16) | f32_to_bf16(v.x);
            unsigned p1 = ((unsigned)f32_to_bf16(v.w) << 16) | f32_to_bf16(v.z);
            *(uint2*)(As + q * 4) = make_uint2(p0, p1);
        }
#pragma unroll
        for (int q = 0; q < 4; q++) {
            uint4 v = *(const uint4*)(Brow + kt + q * 8);
            *(uint4*)(Bs + q * 8) = v;
        }
        __syncthreads();
#pragma unroll
        for (int ks = 0; ks < 2; ks++) {
            bf16x8 af[4], bfr[4];
#pragma unroll
            for (int m = 0; m < 4; m++)
                af[m] = *(const bf16x8*)&Asm[(wm * 64 + m * 16 + lr) * 64 + ks * 32 + lg * 8];
#pragma unroll
            for (int n2 = 0; n2 < 4; n2++)
                bfr[n2] = *(const bf16x8*)&Bsm[(wn * 64 + n2 * 16 + lr) * 64 + ks * 32 + lg * 8];
#pragma unroll
            for (int m = 0; m < 4; m++)
#pragma unroll
                for (int n2 = 0; n2 < 4; n2++)
                    acc[m][n2] = __builtin_amdgcn_mfma_f32_16x16x32_bf16(
                        af[m], bfr[n2], acc[m][n2], 0, 0, 0);
        }
        __syncthreads();
    }
#pragma unroll
    for (int m = 0; m < 4; m++) {
        int r0 = wm * 64 + m * 16 + lg * 4;
#pragma unroll
        for (int n2 = 0; n2 < 4; n2++) {
            int c = wn * 64 + n2 * 16 + lr;
            float bv = bias[c0 + c];
#pragma unroll
            for (int i = 0; i < 4; i++)
                Csm[c][r0 + i] = f32_to_bf16(acc[m][n2][i] + bv);
        }
    }
    __syncthreads();
#pragma unroll
    for (int th = 0; th < 2; th++) {
        uint4* dst = (uint4*)(xT + ((size_t)(t0 + th) * 2048 + c0) * 64);
        for (int q = tid; q < 1024; q += 256) {
            int c = q >> 3, b0 = (q & 7) * 8;
            dst[q] = *(const uint4*)&Csm[c][th * 64 + b0];
        }
        __syncthreads();
    }
}

// ---------------------------------------------------------------------------
// Readout GEMM: A fp32 [M][K], BT bf16 [N][K], C fp32 + bias.
// ---------------------------------------------------------------------------
__global__ __launch_bounds__(256)
void gemm_out_kernel(const float* __restrict__ A, const unsigned short* __restrict__ BT,
                     const float* __restrict__ bias, float* __restrict__ C,
                     int M, int N, int K) {
    __shared__ unsigned short Asm[128 * 64];
    __shared__ unsigned short Bsm[128 * 64];
    const int tid = threadIdx.x;
    const int bm = blockIdx.x, bn = blockIdx.y;
    const int lane = tid & 63, wid = tid >> 6;
    const int wm = wid >> 1, wn = wid & 1;
    const int lr = lane & 15, lg = lane >> 4;

    f32x4 acc[4][4] = {};

    const int srow = tid >> 1, shalf = tid & 1;
    const float* Arow = A + (size_t)(bm * 128 + srow) * K + shalf * 32;
    const unsigned short* Brow = BT + (size_t)(bn * 128 + srow) * K + shalf * 32;
    unsigned short* As = &Asm[srow * 64 + shalf * 32];
    unsigned short* Bs = &Bsm[srow * 64 + shalf * 32];

    for (int kt = 0; kt < K; kt += 64) {
#pragma unroll
        for (int q = 0; q < 8; q++) {
            float4 v = *(const float4*)(Arow + kt + q * 4);
            unsigned p0 = ((unsigned)f32_to_bf16(v.y) << 16) | f32_to_bf16(v.x);
            unsigned p1 = ((unsigned)f32_to_bf16(v.w) << 16) | f32_to_bf16(v.z);
            *(uint2*)(As + q * 4) = make_uint2(p0, p1);
        }
#pragma unroll
        for (int q = 0; q < 4; q++) {
            uint4 v = *(const uint4*)(Brow + kt + q * 8);
            *(uint4*)(Bs + q * 8) = v;
        }
        __syncthreads();
#pragma unroll
        for (int ks = 0; ks < 2; ks++) {
            bf16x8 af[4], bfr[4];
#pragma unroll
            for (int m = 0; m < 4; m++)
                af[m] = *(const bf16x8*)&Asm[(wm * 64 + m * 16 + lr) * 64 + ks * 32 + lg * 8];
#pragma unroll
            for (int n2 = 0; n2 < 4; n2++)
                bfr[n2] = *(const bf16x8*)&Bsm[(wn * 64 + n2 * 16 + lr) * 64 + ks * 32 + lg * 8];
#pragma unroll
            for (int m = 0; m < 4; m++)
#pragma unroll
                for (int n2 = 0; n2 < 4; n2++)
                    acc[m][n2] = __builtin_amdgcn_mfma_f32_16x16x32_bf16(
                        af[m], bfr[n2], acc[m][n2], 0, 0, 0);
        }
        __syncthreads();
    }
#pragma unroll
    for (int m = 0; m < 4; m++) {
        int row0 = bm * 128 + wm * 64 + m * 16 + lg * 4;
#pragma unroll
        for (int n2 = 0; n2 < 4; n2++) {
            int col = bn * 128 + wn * 64 + n2 * 16 + lr;
            float bv = bias[col];
#pragma unroll
            for (int i = 0; i < 4; i++)
                C[(size_t)(row0 + i) * N + col] = acc[m][n2][i] + bv;
        }
    }
}

// ---------------------------------------------------------------------------
// Grid-synced weight-stationary scan with fine-grained producer waits.
// Identical to round 10 EXCEPT spin_fence() after each per-wave wait, which
// restores the ordering edge that rounds 7/8 got from s_barrier.
// Dataflow: wave wv reads hbuf kp in [32wv,32wv+32) and rhrxe k in
// [64wv,64wv+64), produced by exactly blocks 8wv..8wv+7 -> per-wave waits on
// 8 producer flags (lanes 0-7, __all-combined). WAR safety is transitive
// through the flag lattice (audited rounds 9/10); flags monotonic; spins
// bounded.
// ---------------------------------------------------------------------------
__global__ __launch_bounds__(512)
void scan_sync(const unsigned short* __restrict__ xT,   // [512 t][2048 col][64 m] bf16
               const float* __restrict__ h0,            // [64 m][512 j]
               const uint2* __restrict__ warz,          // [256 kp][512 j]
               const uint* __restrict__ wan,            // [512 k][512 j]
               uint* __restrict__ hbuf,                 // [256 kp][64 m]
               uint* __restrict__ rhrxe,                // [512 k][64 m]
               uint* __restrict__ flags,                // flagA[64*4] | flagH[64*4]
               float* __restrict__ hseq)                // [64 m][512 t][512 j]
{
    __shared__ uint2 Wrz_l[256][JO];                    // 16 KB
    __shared__ uint  Wn_l[512][JO];                     // 16 KB
    __shared__ float part[3][8][JO][64];                // 48 KB
    __shared__ float h_loc[JO][64], z_loc[JO][64];      // 4 KB

    const int bid = blockIdx.x, tid = threadIdx.x;
    const int lane = tid & 63, wv = tid >> 6;           // 8 waves
    const int j0 = bid * JO;
    const int jF = tid >> 6, mF = tid & 63;             // finalize mapping

    uint* flagA = flags;                                // set after rhrxe publish
    uint* flagH = flags + 256;                          // set after hbuf publish

    // one-time: weights -> LDS, local h slice
    for (int i = tid; i < 256 * JO; i += 512) {
        int kp = i >> 3, j = i & 7;
        Wrz_l[kp][j] = warz[kp * 512 + j0 + j];
    }
    for (int i = tid; i < 512 * JO; i += 512) {
        int k = i >> 3, j = i & 7;
        Wn_l[k][j] = wan[k * 512 + j0 + j];
    }
    h_loc[jF][mF] = h0[mF * 512 + j0 + jF];
    __syncthreads();

    const int jg = j0 + jF;
    const size_t xoff = (size_t)jg * 64 + mF;
    const bool plane = (lane < 8);                      // poller lanes
    uint* pA = plane ? &flagA[(8 * wv + lane) * 4] : (uint*)0;
    uint* pH = plane ? &flagH[(8 * wv + lane) * 4] : (uint*)0;

    for (int t = 0; t < T_; t++) {
        // xT gate loads: issued before the wait, latency hides under it
        const size_t xb = (size_t)t * 2048 * 64 + xoff;
        unsigned short pxe = xT[xb];
        unsigned short pxr = xT[xb + (size_t)512 * 64];
        unsigned short pxz = xT[xb + (size_t)1024 * 64];
        unsigned short pxn = xT[xb + (size_t)1536 * 64];

        // ---- per-wave wait: h(t) published by my 8 producer blocks ----
        {
            int it = 0; uint f;
            do {
                f = plane ? ald(pH) : 0xFFFFFFFFu;
                if (++it > (1 << 24)) break;            // fail loud, not hang
            } while (!__all(f >= (uint)t));
        }
        spin_fence();   // order the hbuf loads AFTER the spin (rule #18)

        // ---- phase A: r,z partial dots (wave wv covers kp = wv*32..+32) ----
        {
            uint hv[32];
#pragma unroll
            for (int q = 0; q < 32; q++)
                hv[q] = ald(&hbuf[(wv * 32 + q) * 64 + lane]);
            float ar[JO] = {}, az[JO] = {};
#pragma unroll
            for (int q = 0; q < 32; q++) {
                half2_t h2 = uph2(hv[q]);
#pragma unroll
                for (int j = 0; j < JO; j++) {
                    uint2 w = *(const uint2*)&Wrz_l[wv * 32 + q][j];
                    ar[j] = fdot2(h2, uph2(w.x), ar[j]);
                    az[j] = fdot2(h2, uph2(w.y), az[j]);
                }
            }
#pragma unroll
            for (int j = 0; j < JO; j++) {
                part[0][wv][j][lane] = ar[j];
                part[1][wv][j][lane] = az[j];
            }
        }
        __syncthreads();

        // ---- finalize A (all 512 threads; coalesced rhrxe publish) ----
        float xe = bf16_to_f32(pxe), xn_f = bf16_to_f32(pxn);
        {
            float sr = 0.f, sz = 0.f;
#pragma unroll
            for (int w = 0; w < 8; w++) { sr += part[0][w][jF][mF]; sz += part[1][w][jF][mF]; }
            float r = sigmoidf_(bf16_to_f32(pxr) + sr);
            float z = sigmoidf_(bf16_to_f32(pxz) + sz);
            float h = h_loc[jF][mF];
            z_loc[jF][mF] = z;
            ast(&rhrxe[jg * 64 + mF], pkh2(r * h, r * xe));
        }
        __syncthreads();                                // drain rhrxe stores
        if (tid == 0) ast(&flagA[bid * 4], (uint)t + 1u);

        // ---- per-wave wait: rhrxe(t) published by my 8 producer blocks ----
        {
            int it = 0; uint f;
            do {
                f = plane ? ald(pA) : 0xFFFFFFFFu;
                if (++it > (1 << 24)) break;
            } while (!__all(f >= (uint)t + 1u));
        }
        spin_fence();   // order the rhrxe loads AFTER the spin

        // ---- phase B: n partial dots (wave wv covers k = wv*64..+64) ----
        {
            float an[JO] = {};
#pragma unroll
            for (int ch = 0; ch < 2; ch++) {
                uint rv[32];
#pragma unroll
                for (int q = 0; q < 32; q++)
                    rv[q] = ald(&rhrxe[(wv * 64 + ch * 32 + q) * 64 + lane]);
#pragma unroll
                for (int q = 0; q < 32; q++) {
                    half2_t p2 = uph2(rv[q]);
#pragma unroll
                    for (int j = 0; j < JO; j++)
                        an[j] = fdot2(p2, uph2(Wn_l[wv * 64 + ch * 32 + q][j]), an[j]);
                }
            }
#pragma unroll
            for (int j = 0; j < JO; j++) part[2][wv][j][lane] = an[j];
        }
        __syncthreads();

        // ---- finalize B: tanh, h update ----
        {
            float sn = 0.f;
#pragma unroll
            for (int w = 0; w < 8; w++) sn += part[2][w][jF][mF];
            float nn = tanhf(xn_f + sn);
            float z = z_loc[jF][mF];
            float h = h_loc[jF][mF];
            h_loc[jF][mF] = (1.f - z) * h + z * nn;
        }
        __syncthreads();

        // ---- publish new h (f16 pairs) ----
        if (tid < (JO / 2) * 64) {
            int jp = tid >> 6, mh = tid & 63;
            ast(&hbuf[(bid * (JO / 2) + jp) * 64 + mh],
                pkh2(h_loc[2 * jp][mh], h_loc[2 * jp + 1][mh]));
        }
        __syncthreads();                                // drain hbuf stores
        if (tid == 0) ast(&flagH[bid * 4], (uint)t + 1u);

        // ---- hseq write AFTER flag: off the critical drain path ----
        {
            int js = tid & 7, ms = tid >> 3;
            hseq[((size_t)ms * 512 + t) * 512 + j0 + js] = h_loc[js][ms];
        }
    }
}

// ---------------------------------------------------------------------------
extern "C" void kernel_launch(void* const* d_in, const int* in_sizes, int n_in,
                              void* d_out, int out_size, void* d_ws, size_t ws_size,
                              hipStream_t stream) {
    const float* x    = (const float*)d_in[0];
    const float* h0   = (const float*)d_in[1];
    const float* We2h = (const float*)d_in[2];
    const float* Wrx  = (const float*)d_in[3];
    const float* Wrh  = (const float*)d_in[4];
    const float* Wre  = (const float*)d_in[5];
    const float* br   = (const float*)d_in[6];
    const float* Wzx  = (const float*)d_in[7];
    const float* Wzh  = (const float*)d_in[8];
    const float* Wze  = (const float*)d_in[9];
    const float* bz   = (const float*)d_in[10];
    const float* Wnx  = (const float*)d_in[11];
    const float* Wnh  = (const float*)d_in[12];
    const float* Wne  = (const float*)d_in[13];
    const float* bn   = (const float*)d_in[14];
    const float* Wo   = (const float*)d_in[15];
    const float* bo   = (const float*)d_in[16];

    // workspace layout (bytes)
    char* w = (char*)d_ws;
    unsigned short* xT    = (unsigned short*)(w);                  // 134217728
    uint2*          warz  = (uint2*)(w + 134217728);               // 1048576
    uint*           wan   = (uint*)(w + 135266304);                // 1048576
    unsigned short* WcatT = (unsigned short*)(w + 136314880);      // 1048576
    unsigned short* WoT   = (unsigned short*)(w + 137363456);      // 262144
    float*          biascat = (float*)(w + 137625600);             // 8192
    float*          Pr    = (float*)(w + 137633792);               // 524288
    float*          Pz    = (float*)(w + 138158080);               // 524288
    uint*           hbuf  = (uint*)(w + 138682368);                // 65536
    uint*           rhrxe = (uint*)(w + 138747904);                // 131072
    uint*           flags = (uint*)(w + 138878976);                // 2048 (flagA|flagH)

    float* out  = (float*)d_out;                    // [B,T,D]
    float* hseq = (float*)d_out + (size_t)M_ * D_;  // [B,T,H]

    hipMemsetAsync(flags, 0, 2048, stream);

    // 1. composite input weights + packed scan weights
    comp_p<<<(256 * 512 + 255) / 256, 256, 0, stream>>>(We2h, Wre, Wze, Pr, Pz);
    build_wt<<<(2048 * 256 + 256 * 512 + 255) / 256, 256, 0, stream>>>(
        We2h, Wrx, Wzx, Wnx, Pr, Pz, br, bz, bn, Wo, WcatT, biascat, WoT);
    build_wscan<<<(256 * 512 + 512 * 512 + 255) / 256, 256, 0, stream>>>(
        Wrh, Wre, Wzh, Wze, Wnh, Wne, warz, wan);
    init_hbuf<<<(256 * 64 + 255) / 256, 256, 0, stream>>>(h0, hbuf);

    // 2. pre-projections directly into xT[t][col][m]
    {
        dim3 grid(T_ / 2, 2048 / 128);
        gemmx_kernel<<<grid, 256, 0, stream>>>(x, WcatT, biascat, xT);
    }
    // 3. grid-synced scan -> hseq
    scan_sync<<<NBLK, 512, 0, stream>>>(xT, h0, warz, wan, hbuf, rhrxe, flags, hseq);
    // 4. readout: [32768,512] @ [512,256] + bo -> out
    {
        dim3 grid(M_ / 128, D_ / 128);
        gemm_out_kernel<<<grid, 256, 0, stream>>>(hseq, WoT, bo, out, M_, D_, H_);
    }
}